// Round 1
// baseline (34951.474 us; speedup 1.0000x reference)
//
#include <hip/hip_runtime.h>
#include <stdint.h>

// dims (fixed by the problem)
#define NCC 8192     // n_chars
#define NWW 2048     // n_words
#define ECH 128      // char emb dim
#define HCH 256      // char hidden
#define EWD 1024     // word emb dim
#define HWD 1024     // word hidden
#define TGT 64       // tagset

#define SENT 0x40000000u   // 2.0f — impossible for h = o*tanh(c), |h| < 1

__device__ __forceinline__ float fsig(float x) { return 1.0f / (1.0f + __expf(-x)); }
__device__ __forceinline__ float ftanh_(float x) {
    float ax = fabsf(x);
    float e  = __expf(-2.0f * ax);
    float t  = (1.0f - e) / (1.0f + e);
    return copysignf(t, x);
}

__device__ __forceinline__ unsigned ldA(const unsigned* p) {
    return __hip_atomic_load(p, __ATOMIC_RELAXED, __HIP_MEMORY_SCOPE_AGENT);
}
__device__ __forceinline__ void stA(unsigned* p, unsigned v) {
    __hip_atomic_store(p, v, __ATOMIC_RELAXED, __HIP_MEMORY_SCOPE_AGENT);
}

// ---------------------------------------------------------------------------
// reset: h ring buffers -> sentinel, row 0 -> zeros (initial hidden state)
// ---------------------------------------------------------------------------
__global__ void reset_ws(unsigned* __restrict__ hc, unsigned* __restrict__ hw) {
    long i = (long)blockIdx.x * blockDim.x + threadIdx.x;
    long stride = (long)gridDim.x * blockDim.x;
    const long nhc = (long)(NCC + 1) * HCH;
    const long nhw = (long)(NWW + 1) * HWD;
    for (long j = i; j < nhc; j += stride) hc[j] = (j < HCH) ? 0u : SENT;
    for (long j = i; j < nhw; j += stride) hw[j] = (j < HWD) ? 0u : SENT;
}

// ---------------------------------------------------------------------------
// generic gather-GEMM: C[m][n] (+)= sum_k A[idx[m]+add][k] * B[n][k] + bias(n)
// A rows gathered (idx may be null -> identity), row length = lda (= K here).
// 128x128 tile, BK=32, 256 threads, 8x8 microtile.
// ---------------------------------------------------------------------------
#define BM 128
#define BN 128
#define BK 32

__global__ __launch_bounds__(256) void gemm_gather(
    const float* __restrict__ A, const int* __restrict__ idx, const int idxAdd, const int lda,
    const float* __restrict__ B, const int ldb,
    const float* __restrict__ bias1, const float* __restrict__ bias2,
    float* __restrict__ C, const int ldc,
    const int K, const int doAcc)
{
    __shared__ __align__(16) float As[BK][BM + 4];
    __shared__ __align__(16) float Bs[BK][BN + 4];

    const int tid = threadIdx.x;
    const int bm = blockIdx.y * BM, bn = blockIdx.x * BN;
    const int tx = tid & 15, ty = tid >> 4;

    const int lr = tid >> 3;          // 0..31
    const int lc = (tid & 7) * 4;     // 0,4,...,28

    const float* arow[4];
    const float* brow[4];
#pragma unroll
    for (int p = 0; p < 4; ++p) {
        int r  = lr + p * 32;
        int am = bm + r;
        long arI = idx ? ((long)idx[am] + idxAdd) : (long)am;
        arow[p] = A + arI * (long)lda + lc;
        brow[p] = B + (long)(bn + r) * ldb + lc;
    }

    float acc[8][8];
#pragma unroll
    for (int i = 0; i < 8; ++i)
#pragma unroll
        for (int j = 0; j < 8; ++j) acc[i][j] = 0.f;

    for (int k0 = 0; k0 < K; k0 += BK) {
#pragma unroll
        for (int p = 0; p < 4; ++p) {
            int r = lr + p * 32;
            float4 av = *(const float4*)(arow[p] + k0);
            float4 bv = *(const float4*)(brow[p] + k0);
            As[lc + 0][r] = av.x; As[lc + 1][r] = av.y; As[lc + 2][r] = av.z; As[lc + 3][r] = av.w;
            Bs[lc + 0][r] = bv.x; Bs[lc + 1][r] = bv.y; Bs[lc + 2][r] = bv.z; Bs[lc + 3][r] = bv.w;
        }
        __syncthreads();
#pragma unroll
        for (int kk = 0; kk < BK; ++kk) {
            float a[8], b[8];
            *(float4*)&a[0] = *(const float4*)&As[kk][ty * 8];
            *(float4*)&a[4] = *(const float4*)&As[kk][ty * 8 + 4];
            *(float4*)&b[0] = *(const float4*)&Bs[kk][tx * 8];
            *(float4*)&b[4] = *(const float4*)&Bs[kk][tx * 8 + 4];
#pragma unroll
            for (int i = 0; i < 8; ++i)
#pragma unroll
                for (int j = 0; j < 8; ++j)
                    acc[i][j] = fmaf(a[i], b[j], acc[i][j]);
        }
        __syncthreads();
    }

#pragma unroll
    for (int i = 0; i < 8; ++i) {
        long row = bm + ty * 8 + i;
        float* cp = C + row * (long)ldc + bn + tx * 8;
#pragma unroll
        for (int q = 0; q < 2; ++q) {
            int n0 = bn + tx * 8 + q * 4;
            float4 v = make_float4(acc[i][q * 4 + 0], acc[i][q * 4 + 1],
                                   acc[i][q * 4 + 2], acc[i][q * 4 + 3]);
            if (bias1) {
                float4 b1 = *(const float4*)(bias1 + n0);
                float4 b2 = *(const float4*)(bias2 + n0);
                v.x += b1.x + b2.x; v.y += b1.y + b2.y;
                v.z += b1.z + b2.z; v.w += b1.w + b2.w;
            }
            if (doAcc) {
                float4 o = *(const float4*)(cp + q * 4);
                v.x += o.x; v.y += o.y; v.z += o.z; v.w += o.w;
            }
            *(float4*)(cp + q * 4) = v;
        }
    }
}

// ---------------------------------------------------------------------------
// char LSTM: 64 WGs x 256 thr. WG owns 4 hidden units (1 per wave).
// Wave layout: g = lane>>4 (gate i,f,g,o), s = lane&15 (16-col slice).
// Per step: each thread polls ONE h value (data-is-flag) -> LDS broadcast ->
// 16-wide dot -> 4-round shuffle reduce -> +pre -> xor16/32/48 gate transpose
// -> lane0 nonlinearities, cell update, agent-scope h store.
// ---------------------------------------------------------------------------
__global__ __launch_bounds__(256) void char_lstm(
    const float* __restrict__ pre, const float* __restrict__ Whh, unsigned* __restrict__ hc)
{
    const int tid  = threadIdx.x;
    const int wave = tid >> 6;
    const int l    = tid & 63;
    const int g    = l >> 4;
    const int s    = l & 15;
    const int hu   = blockIdx.x * 4 + wave;

    __shared__ __align__(16) float hsm[2][HCH + 48];  // +12 pad per 64 floats

    float w[16];
    {
        const float* wp = Whh + (long)(g * HCH + hu) * HCH + s * 16;
#pragma unroll
        for (int j = 0; j < 16; ++j) w[j] = wp[j];
    }
    float cc = 0.f;

    const int pIdx = tid + (tid >> 6) * 12;
    const int rIdx = s * 16 + (s >> 2) * 12;
    const float*    prep  = pre + g * HCH + hu;
    const unsigned* pollp = hc + tid;
    unsigned*       stp   = hc + HCH + hu;

    for (int t = 0; t < NCC; ++t) {
        float pv = prep[(long)t * (4 * HCH)];
        unsigned uv;
        do { uv = ldA(pollp + (long)t * HCH); } while (uv == SENT);
        hsm[t & 1][pIdx] = __uint_as_float(uv);
        __syncthreads();

        const float* hp = &hsm[t & 1][rIdx];
        float sum = 0.f;
#pragma unroll
        for (int q = 0; q < 4; ++q) {
            float4 hv = *(const float4*)(hp + q * 4);
            sum = fmaf(hv.x, w[q * 4 + 0], sum);
            sum = fmaf(hv.y, w[q * 4 + 1], sum);
            sum = fmaf(hv.z, w[q * 4 + 2], sum);
            sum = fmaf(hv.w, w[q * 4 + 3], sum);
        }
        sum += __shfl_xor(sum, 1);
        sum += __shfl_xor(sum, 2);
        sum += __shfl_xor(sum, 4);
        sum += __shfl_xor(sum, 8);
        sum += pv;
        float s1 = __shfl_xor(sum, 16);
        float s2 = __shfl_xor(sum, 32);
        float s3 = __shfl_xor(sum, 48);
        if (l == 0) {
            float i_ = fsig(sum), f_ = fsig(s1), g_ = ftanh_(s2), o_ = fsig(s3);
            cc = fmaf(f_, cc, i_ * g_);
            float h = o_ * ftanh_(cc);
            stA(stp + (long)t * HCH, __float_as_uint(h));
        }
    }
}

// ---------------------------------------------------------------------------
// word LSTM: 256 WGs x 256 thr. WG owns 4 hidden units (1 per wave).
// Same structure; thread polls 4 h values, lane covers 64 cols.
// ---------------------------------------------------------------------------
__global__ __launch_bounds__(256) void word_lstm(
    const float* __restrict__ pre, const float* __restrict__ Whh, unsigned* __restrict__ hw)
{
    const int tid  = threadIdx.x;
    const int wave = tid >> 6;
    const int l    = tid & 63;
    const int g    = l >> 4;
    const int s    = l & 15;
    const int hu   = blockIdx.x * 4 + wave;   // 0..1023

    __shared__ __align__(16) float hsm[2][HWD + 192];  // +12 pad per 64 floats

    float w[64];
    {
        const float* wp = Whh + (long)(g * HWD + hu) * HWD + s * 64;
#pragma unroll
        for (int j = 0; j < 64; ++j) w[j] = wp[j];
    }
    float cc = 0.f;

    const int pc   = tid * 4;
    const int pIdx = pc + (pc >> 6) * 12;
    const int rIdx = s * 76;                  // s*64 + s*12
    const float*    prep  = pre + g * HWD + hu;
    const unsigned* pollp = hw + pc;
    unsigned*       stp   = hw + HWD + hu;

    for (int t = 0; t < NWW; ++t) {
        float pv = prep[(long)t * (4 * HWD)];
        const unsigned* pp = pollp + (long)t * HWD;
        unsigned u0, u1, u2, u3;
        bool rdy;
        do {
            u0 = ldA(pp + 0); u1 = ldA(pp + 1); u2 = ldA(pp + 2); u3 = ldA(pp + 3);
            rdy = (u0 != SENT) & (u1 != SENT) & (u2 != SENT) & (u3 != SENT);
        } while (!rdy);
        *(float4*)&hsm[t & 1][pIdx] = make_float4(
            __uint_as_float(u0), __uint_as_float(u1),
            __uint_as_float(u2), __uint_as_float(u3));
        __syncthreads();

        const float* hp = &hsm[t & 1][rIdx];
        float sum = 0.f;
#pragma unroll
        for (int q = 0; q < 16; ++q) {
            float4 hv = *(const float4*)(hp + q * 4);
            sum = fmaf(hv.x, w[q * 4 + 0], sum);
            sum = fmaf(hv.y, w[q * 4 + 1], sum);
            sum = fmaf(hv.z, w[q * 4 + 2], sum);
            sum = fmaf(hv.w, w[q * 4 + 3], sum);
        }
        sum += __shfl_xor(sum, 1);
        sum += __shfl_xor(sum, 2);
        sum += __shfl_xor(sum, 4);
        sum += __shfl_xor(sum, 8);
        sum += pv;
        float s1 = __shfl_xor(sum, 16);
        float s2 = __shfl_xor(sum, 32);
        float s3 = __shfl_xor(sum, 48);
        if (l == 0) {
            float i_ = fsig(sum), f_ = fsig(s1), g_ = ftanh_(s2), o_ = fsig(s3);
            cc = fmaf(f_, cc, i_ * g_);
            float h = o_ * ftanh_(cc);
            stA(stp + (long)t * HWD, __float_as_uint(h));
        }
    }
}

// ---------------------------------------------------------------------------
// tag head: logits = h @ W_tag.T + b_tag ; log_softmax per row.
// One wave per word row (T = 64 = wave width), 4 rows per block.
// ---------------------------------------------------------------------------
__global__ __launch_bounds__(256) void tag_softmax(
    const float* __restrict__ hw, const float* __restrict__ Wtag,
    const float* __restrict__ btag, float* __restrict__ out)
{
    const int wave = threadIdx.x >> 6, l = threadIdx.x & 63;
    const int r = blockIdx.x * 4 + wave;
    const float* hrow = hw + (long)(r + 1) * HWD;
    const float* wrow = Wtag + (long)l * HWD;
    float acc = 0.f;
    for (int k = 0; k < HWD; k += 4) {
        float4 h4 = *(const float4*)(hrow + k);
        float4 w4 = *(const float4*)(wrow + k);
        acc = fmaf(h4.x, w4.x, acc);
        acc = fmaf(h4.y, w4.y, acc);
        acc = fmaf(h4.z, w4.z, acc);
        acc = fmaf(h4.w, w4.w, acc);
    }
    acc += btag[l];
    float m = acc;
#pragma unroll
    for (int msk = 32; msk; msk >>= 1) m = fmaxf(m, __shfl_xor(m, msk));
    float e = __expf(acc - m);
    float ssum = e;
#pragma unroll
    for (int msk = 32; msk; msk >>= 1) ssum += __shfl_xor(ssum, msk);
    out[(long)r * TGT + l] = acc - m - logf(ssum);
}

// ---------------------------------------------------------------------------
extern "C" void kernel_launch(void* const* d_in, const int* in_sizes, int n_in,
                              void* d_out, int out_size, void* d_ws, size_t ws_size,
                              hipStream_t stream)
{
    (void)in_sizes; (void)n_in; (void)out_size; (void)ws_size;

    const int*   ix_c = (const int*)  d_in[0];
    const int*   ix   = (const int*)  d_in[1];
    const int*   offs = (const int*)  d_in[2];
    const float* cemb = (const float*)d_in[3];
    const float* emb  = (const float*)d_in[4];
    const float* Wihc = (const float*)d_in[5];
    const float* Whhc = (const float*)d_in[6];
    const float* bihc = (const float*)d_in[7];
    const float* bhhc = (const float*)d_in[8];
    const float* Wih  = (const float*)d_in[9];
    const float* Whh  = (const float*)d_in[10];
    const float* bih  = (const float*)d_in[11];
    const float* bhh  = (const float*)d_in[12];
    const float* Wtag = (const float*)d_in[13];
    const float* btag = (const float*)d_in[14];

    float* ws   = (float*)d_ws;
    float* hc   = ws;                                    // (NCC+1)*HCH
    float* hwv  = hc   + (long)(NCC + 1) * HCH;          // (NWW+1)*HWD
    float* prec = hwv  + (long)(NWW + 1) * HWD;          // NCC*4*HCH
    float* prew = prec + (long)NCC * 4 * HCH;            // NWW*4*HWD
    // total: 83.9 MB of f32 workspace

    // 1) sentinel/zero reset of the h exchange buffers (every call)
    reset_ws<<<dim3(1024), dim3(256), 0, stream>>>((unsigned*)hc, (unsigned*)hwv);

    // 2) pre_c = char_emb[ix_c] @ W_ih_c^T + (b_ih_c + b_hh_c)   [8192 x 1024]
    gemm_gather<<<dim3((4 * HCH) / BN, NCC / BM), dim3(256), 0, stream>>>(
        cemb, ix_c, 0, ECH, Wihc, ECH, bihc, bhhc, prec, 4 * HCH, ECH, 0);

    // 3) pre_w (emb part) = emb[ix] @ W_ih[:, :1024]^T + (b_ih + b_hh)  [2048 x 4096]
    gemm_gather<<<dim3((4 * HWD) / BN, NWW / BM), dim3(256), 0, stream>>>(
        emb, ix, 0, EWD, Wih, EWD + HCH, bih, bhh, prew, 4 * HWD, EWD, 0);

    // 4) char LSTM (8192 sequential steps, persistent, data-flag polling)
    char_lstm<<<dim3(HCH / 4), dim3(256), 0, stream>>>(prec, Whhc, (unsigned*)hc);

    // 5) pre_w += chars_out[offsets] @ W_ih[:, 1024:]^T   [K = 256, accumulate]
    gemm_gather<<<dim3((4 * HWD) / BN, NWW / BM), dim3(256), 0, stream>>>(
        hc, offs, 1, HCH, Wih + EWD, EWD + HCH,
        (const float*)nullptr, (const float*)nullptr, prew, 4 * HWD, HCH, 1);

    // 6) word LSTM (2048 sequential steps)
    word_lstm<<<dim3(HWD / 4), dim3(256), 0, stream>>>(prew, Whh, (unsigned*)hwv);

    // 7) tag head + log_softmax -> d_out [2048 x 64] f32
    tag_softmax<<<dim3(NWW / 4), dim3(256), 0, stream>>>(hwv, Wtag, btag, (float*)d_out);
}

// Round 2
// 30095.163 us; speedup vs baseline: 1.1614x; 1.1614x over previous
//
#include <hip/hip_runtime.h>
#include <stdint.h>

// dims (fixed by the problem)
#define NCC 8192     // n_chars
#define NWW 2048     // n_words
#define ECH 128      // char emb dim
#define HCH 256      // char hidden
#define EWD 1024     // word emb dim
#define HWD 1024     // word hidden
#define TGT 64       // tagset

#define SENT 0x40000000u   // 2.0f — impossible for h = o*tanh(c), |h| < 1

__device__ __forceinline__ float fsig(float x) { return 1.0f / (1.0f + __expf(-x)); }
__device__ __forceinline__ float ftanh_(float x) {
    float ax = fabsf(x);
    float e  = __expf(-2.0f * ax);
    float t  = (1.0f - e) / (1.0f + e);
    return copysignf(t, x);
}

__device__ __forceinline__ unsigned long long ldA64(const unsigned long long* p) {
    return __hip_atomic_load(p, __ATOMIC_RELAXED, __HIP_MEMORY_SCOPE_AGENT);
}
__device__ __forceinline__ void stA(unsigned* p, unsigned v) {
    __hip_atomic_store(p, v, __ATOMIC_RELAXED, __HIP_MEMORY_SCOPE_AGENT);
}

// ---------------------------------------------------------------------------
// reset: h ring buffers -> sentinel, row 0 -> zeros (initial hidden state)
// ---------------------------------------------------------------------------
__global__ void reset_ws(unsigned* __restrict__ hc, unsigned* __restrict__ hw) {
    long i = (long)blockIdx.x * blockDim.x + threadIdx.x;
    long stride = (long)gridDim.x * blockDim.x;
    const long nhc = (long)(NCC + 1) * HCH;
    const long nhw = (long)(NWW + 1) * HWD;
    for (long j = i; j < nhc; j += stride) hc[j] = (j < HCH) ? 0u : SENT;
    for (long j = i; j < nhw; j += stride) hw[j] = (j < HWD) ? 0u : SENT;
}

// ---------------------------------------------------------------------------
// generic gather-GEMM: C[m][n] (+)= sum_k A[idx[m]+add][k] * B[n][k] + bias(n)
// 128x128 tile, BK=32, 256 threads, 8x8 microtile.
// ---------------------------------------------------------------------------
#define BM 128
#define BN 128
#define BK 32

__global__ __launch_bounds__(256) void gemm_gather(
    const float* __restrict__ A, const int* __restrict__ idx, const int idxAdd, const int lda,
    const float* __restrict__ B, const int ldb,
    const float* __restrict__ bias1, const float* __restrict__ bias2,
    float* __restrict__ C, const int ldc,
    const int K, const int doAcc)
{
    __shared__ __align__(16) float As[BK][BM + 4];
    __shared__ __align__(16) float Bs[BK][BN + 4];

    const int tid = threadIdx.x;
    const int bm = blockIdx.y * BM, bn = blockIdx.x * BN;
    const int tx = tid & 15, ty = tid >> 4;

    const int lr = tid >> 3;          // 0..31
    const int lc = (tid & 7) * 4;     // 0,4,...,28

    const float* arow[4];
    const float* brow[4];
#pragma unroll
    for (int p = 0; p < 4; ++p) {
        int r  = lr + p * 32;
        int am = bm + r;
        long arI = idx ? ((long)idx[am] + idxAdd) : (long)am;
        arow[p] = A + arI * (long)lda + lc;
        brow[p] = B + (long)(bn + r) * ldb + lc;
    }

    float acc[8][8];
#pragma unroll
    for (int i = 0; i < 8; ++i)
#pragma unroll
        for (int j = 0; j < 8; ++j) acc[i][j] = 0.f;

    for (int k0 = 0; k0 < K; k0 += BK) {
#pragma unroll
        for (int p = 0; p < 4; ++p) {
            int r = lr + p * 32;
            float4 av = *(const float4*)(arow[p] + k0);
            float4 bv = *(const float4*)(brow[p] + k0);
            As[lc + 0][r] = av.x; As[lc + 1][r] = av.y; As[lc + 2][r] = av.z; As[lc + 3][r] = av.w;
            Bs[lc + 0][r] = bv.x; Bs[lc + 1][r] = bv.y; Bs[lc + 2][r] = bv.z; Bs[lc + 3][r] = bv.w;
        }
        __syncthreads();
#pragma unroll
        for (int kk = 0; kk < BK; ++kk) {
            float a[8], b[8];
            *(float4*)&a[0] = *(const float4*)&As[kk][ty * 8];
            *(float4*)&a[4] = *(const float4*)&As[kk][ty * 8 + 4];
            *(float4*)&b[0] = *(const float4*)&Bs[kk][tx * 8];
            *(float4*)&b[4] = *(const float4*)&Bs[kk][tx * 8 + 4];
#pragma unroll
            for (int i = 0; i < 8; ++i)
#pragma unroll
                for (int j = 0; j < 8; ++j)
                    acc[i][j] = fmaf(a[i], b[j], acc[i][j]);
        }
        __syncthreads();
    }

#pragma unroll
    for (int i = 0; i < 8; ++i) {
        long row = bm + ty * 8 + i;
        float* cp = C + row * (long)ldc + bn + tx * 8;
#pragma unroll
        for (int q = 0; q < 2; ++q) {
            int n0 = bn + tx * 8 + q * 4;
            float4 v = make_float4(acc[i][q * 4 + 0], acc[i][q * 4 + 1],
                                   acc[i][q * 4 + 2], acc[i][q * 4 + 3]);
            if (bias1) {
                float4 b1 = *(const float4*)(bias1 + n0);
                float4 b2 = *(const float4*)(bias2 + n0);
                v.x += b1.x + b2.x; v.y += b1.y + b2.y;
                v.z += b1.z + b2.z; v.w += b1.w + b2.w;
            }
            if (doAcc) {
                float4 o = *(const float4*)(cp + q * 4);
                v.x += o.x; v.y += o.y; v.z += o.z; v.w += o.w;
            }
            *(float4*)(cp + q * 4) = v;
        }
    }
}

// ---------------------------------------------------------------------------
// char LSTM: 8 WGs x 1024 thr. WG owns 32 units (2 per wave).
// lane = half*32 + gate*8 + seg. Thread: 32-MAC dot slice (seg of 256).
// 128 pollers @ 8B granularity w/ s_sleep backoff; own block via LDS.
// Producer: ONE coalesced 32-dword store per WG per step.
// ---------------------------------------------------------------------------
__global__ __launch_bounds__(1024) void char_lstm(
    const float* __restrict__ pre, const float* __restrict__ Whh, unsigned* __restrict__ hglob)
{
    const int tid  = threadIdx.x;
    const int lane = tid & 63;
    const int wave = tid >> 6;            // 0..15
    const int half = lane >> 5;           // 0/1
    const int l32  = lane & 31;
    const int gate = l32 >> 3;            // 0..3
    const int seg  = l32 & 7;             // 0..7
    const int uloc = wave * 2 + half;     // 0..31
    const int unit = blockIdx.x * 32 + uloc;

    __shared__ float hloc[32];
    __shared__ __align__(16) float hb[2][352];   // stride 44 floats per 32 (16B-aligned, conflict-free)

    float w[32];
    {
        const float* wp = Whh + ((long)(gate * HCH + unit)) * HCH + seg * 32;
#pragma unroll
        for (int j = 0; j < 32; j += 4) {
            float4 v = *(const float4*)(wp + j);
            w[j] = v.x; w[j+1] = v.y; w[j+2] = v.z; w[j+3] = v.w;
        }
    }
    if (tid < 32) hloc[tid] = 0.f;
    __syncthreads();

    float cc = 0.f;
    const float* prep = pre + gate * HCH + unit;

    const int  pair     = tid;                    // tid<128: values 2p, 2p+1
    const bool isPoller = (tid < 128);
    const bool isOwn    = isPoller && (pair >= blockIdx.x * 16) && (pair < blockIdx.x * 16 + 16);
    const int  ownL     = pair * 2 - blockIdx.x * 32;
    const int  wIdx     = 2 * pair + ((2 * pair) >> 5) * 12;
    const int  rBase    = seg * 44;
    unsigned*  stp      = hglob + HCH + blockIdx.x * 32 + tid;   // row t+1, tid<32

    for (int t = 0; t < NCC; ++t) {
        float pv = prep[(long)t * (4 * HCH)];
        const int cur = t & 1;
        if (isPoller) {
            float v0, v1;
            if (isOwn) { v0 = hloc[ownL]; v1 = hloc[ownL + 1]; }
            else {
                const unsigned long long* p =
                    (const unsigned long long*)(hglob + (long)t * HCH + 2 * pair);
                unsigned long long uv;
                for (;;) {
                    uv = ldA64(p);
                    if ((unsigned)uv != SENT && (unsigned)(uv >> 32) != SENT) break;
                    __builtin_amdgcn_s_sleep(1);
                }
                v0 = __uint_as_float((unsigned)uv);
                v1 = __uint_as_float((unsigned)(uv >> 32));
            }
            hb[cur][wIdx] = v0; hb[cur][wIdx + 1] = v1;
        }
        __syncthreads();

        const float* hp = &hb[cur][rBase];
        float sum = 0.f;
#pragma unroll
        for (int q = 0; q < 8; ++q) {
            float4 hv = *(const float4*)(hp + q * 4);
            sum = fmaf(hv.x, w[q * 4 + 0], sum);
            sum = fmaf(hv.y, w[q * 4 + 1], sum);
            sum = fmaf(hv.z, w[q * 4 + 2], sum);
            sum = fmaf(hv.w, w[q * 4 + 3], sum);
        }
        sum += __shfl_xor(sum, 1);
        sum += __shfl_xor(sum, 2);
        sum += __shfl_xor(sum, 4);
        sum += pv;
        float f_s = __shfl_xor(sum, 8);
        float g_s = __shfl_xor(sum, 16);
        float o_s = __shfl_xor(sum, 24);
        if (l32 == 0) {
            float i_ = fsig(sum), f_ = fsig(f_s), g_ = ftanh_(g_s), o_ = fsig(o_s);
            cc = fmaf(f_, cc, i_ * g_);
            hloc[uloc] = o_ * ftanh_(cc);
        }
        __syncthreads();
        if (tid < 32)
            stA(stp + (long)t * HCH, __float_as_uint(hloc[tid]));
    }
}

// ---------------------------------------------------------------------------
// word LSTM: 64 WGs x 1024 thr. WG owns 16 units (1 per wave).
// lane = gate*16 + seg. Thread: 64-MAC dot slice (seg of 1024).
// 512 pollers @ 8B granularity; producer ONE 16-dword (64B) store per step.
// ---------------------------------------------------------------------------
__global__ __launch_bounds__(1024) void word_lstm(
    const float* __restrict__ pre, const float* __restrict__ Whh, unsigned* __restrict__ hglob)
{
    const int tid  = threadIdx.x;
    const int lane = tid & 63;
    const int wave = tid >> 6;            // 0..15 = local unit
    const int gate = lane >> 4;
    const int seg  = lane & 15;
    const int unit = blockIdx.x * 16 + wave;

    __shared__ float hloc[16];
    __shared__ __align__(16) float hb[2][1208];  // stride 76 floats per 64 (16B-aligned, 2-way)

    float w[64];
    {
        const float* wp = Whh + ((long)(gate * HWD + unit)) * HWD + seg * 64;
#pragma unroll
        for (int j = 0; j < 64; j += 4) {
            float4 v = *(const float4*)(wp + j);
            w[j] = v.x; w[j+1] = v.y; w[j+2] = v.z; w[j+3] = v.w;
        }
    }
    if (tid < 16) hloc[tid] = 0.f;
    __syncthreads();

    float cc = 0.f;
    const float* prep = pre + gate * HWD + unit;

    const int  pair     = tid;                    // tid<512: values 2p, 2p+1
    const bool isPoller = (tid < 512);
    const bool isOwn    = isPoller && (pair >= blockIdx.x * 8) && (pair < blockIdx.x * 8 + 8);
    const int  ownL     = pair * 2 - blockIdx.x * 16;
    const int  wIdx     = 2 * pair + ((2 * pair) >> 6) * 12;
    const int  rBase    = seg * 76;
    unsigned*  stp      = hglob + HWD + blockIdx.x * 16 + tid;   // row t+1, tid<16

    for (int t = 0; t < NWW; ++t) {
        float pv = prep[(long)t * (4 * HWD)];
        const int cur = t & 1;
        if (isPoller) {
            float v0, v1;
            if (isOwn) { v0 = hloc[ownL]; v1 = hloc[ownL + 1]; }
            else {
                const unsigned long long* p =
                    (const unsigned long long*)(hglob + (long)t * HWD + 2 * pair);
                unsigned long long uv;
                for (;;) {
                    uv = ldA64(p);
                    if ((unsigned)uv != SENT && (unsigned)(uv >> 32) != SENT) break;
                    __builtin_amdgcn_s_sleep(1);
                }
                v0 = __uint_as_float((unsigned)uv);
                v1 = __uint_as_float((unsigned)(uv >> 32));
            }
            hb[cur][wIdx] = v0; hb[cur][wIdx + 1] = v1;
        }
        __syncthreads();

        const float* hp = &hb[cur][rBase];
        float sum = 0.f;
#pragma unroll
        for (int q = 0; q < 16; ++q) {
            float4 hv = *(const float4*)(hp + q * 4);
            sum = fmaf(hv.x, w[q * 4 + 0], sum);
            sum = fmaf(hv.y, w[q * 4 + 1], sum);
            sum = fmaf(hv.z, w[q * 4 + 2], sum);
            sum = fmaf(hv.w, w[q * 4 + 3], sum);
        }
        sum += __shfl_xor(sum, 1);
        sum += __shfl_xor(sum, 2);
        sum += __shfl_xor(sum, 4);
        sum += __shfl_xor(sum, 8);
        sum += pv;
        float f_s = __shfl_xor(sum, 16);
        float g_s = __shfl_xor(sum, 32);
        float o_s = __shfl_xor(sum, 48);
        if (lane == 0) {
            float i_ = fsig(sum), f_ = fsig(f_s), g_ = ftanh_(g_s), o_ = fsig(o_s);
            cc = fmaf(f_, cc, i_ * g_);
            hloc[wave] = o_ * ftanh_(cc);
        }
        __syncthreads();
        if (tid < 16)
            stA(stp + (long)t * HWD, __float_as_uint(hloc[tid]));
    }
}

// ---------------------------------------------------------------------------
// tag head: logits = h @ W_tag.T + b_tag ; log_softmax per row.
// ---------------------------------------------------------------------------
__global__ __launch_bounds__(256) void tag_softmax(
    const float* __restrict__ hw, const float* __restrict__ Wtag,
    const float* __restrict__ btag, float* __restrict__ out)
{
    const int wave = threadIdx.x >> 6, l = threadIdx.x & 63;
    const int r = blockIdx.x * 4 + wave;
    const float* hrow = hw + (long)(r + 1) * HWD;
    const float* wrow = Wtag + (long)l * HWD;
    float acc = 0.f;
    for (int k = 0; k < HWD; k += 4) {
        float4 h4 = *(const float4*)(hrow + k);
        float4 w4 = *(const float4*)(wrow + k);
        acc = fmaf(h4.x, w4.x, acc);
        acc = fmaf(h4.y, w4.y, acc);
        acc = fmaf(h4.z, w4.z, acc);
        acc = fmaf(h4.w, w4.w, acc);
    }
    acc += btag[l];
    float m = acc;
#pragma unroll
    for (int msk = 32; msk; msk >>= 1) m = fmaxf(m, __shfl_xor(m, msk));
    float e = __expf(acc - m);
    float ssum = e;
#pragma unroll
    for (int msk = 32; msk; msk >>= 1) ssum += __shfl_xor(ssum, msk);
    out[(long)r * TGT + l] = acc - m - logf(ssum);
}

// ---------------------------------------------------------------------------
extern "C" void kernel_launch(void* const* d_in, const int* in_sizes, int n_in,
                              void* d_out, int out_size, void* d_ws, size_t ws_size,
                              hipStream_t stream)
{
    (void)in_sizes; (void)n_in; (void)out_size; (void)ws_size;

    const int*   ix_c = (const int*)  d_in[0];
    const int*   ix   = (const int*)  d_in[1];
    const int*   offs = (const int*)  d_in[2];
    const float* cemb = (const float*)d_in[3];
    const float* emb  = (const float*)d_in[4];
    const float* Wihc = (const float*)d_in[5];
    const float* Whhc = (const float*)d_in[6];
    const float* bihc = (const float*)d_in[7];
    const float* bhhc = (const float*)d_in[8];
    const float* Wih  = (const float*)d_in[9];
    const float* Whh  = (const float*)d_in[10];
    const float* bih  = (const float*)d_in[11];
    const float* bhh  = (const float*)d_in[12];
    const float* Wtag = (const float*)d_in[13];
    const float* btag = (const float*)d_in[14];

    float* ws   = (float*)d_ws;
    float* hc   = ws;                                    // (NCC+1)*HCH
    float* hwv  = hc   + (long)(NCC + 1) * HCH;          // (NWW+1)*HWD
    float* prec = hwv  + (long)(NWW + 1) * HWD;          // NCC*4*HCH
    float* prew = prec + (long)NCC * 4 * HCH;            // NWW*4*HWD

    // 1) sentinel/zero reset of the h exchange buffers (every call)
    reset_ws<<<dim3(1024), dim3(256), 0, stream>>>((unsigned*)hc, (unsigned*)hwv);

    // 2) pre_c = char_emb[ix_c] @ W_ih_c^T + (b_ih_c + b_hh_c)   [8192 x 1024]
    gemm_gather<<<dim3((4 * HCH) / BN, NCC / BM), dim3(256), 0, stream>>>(
        cemb, ix_c, 0, ECH, Wihc, ECH, bihc, bhhc, prec, 4 * HCH, ECH, 0);

    // 3) pre_w (emb part) = emb[ix] @ W_ih[:, :1024]^T + (b_ih + b_hh)  [2048 x 4096]
    gemm_gather<<<dim3((4 * HWD) / BN, NWW / BM), dim3(256), 0, stream>>>(
        emb, ix, 0, EWD, Wih, EWD + HCH, bih, bhh, prew, 4 * HWD, EWD, 0);

    // 4) char LSTM: 8 WGs x 1024 threads
    char_lstm<<<dim3(8), dim3(1024), 0, stream>>>(prec, Whhc, (unsigned*)hc);

    // 5) pre_w += chars_out[offsets] @ W_ih[:, 1024:]^T   [K = 256, accumulate]
    gemm_gather<<<dim3((4 * HWD) / BN, NWW / BM), dim3(256), 0, stream>>>(
        hc, offs, 1, HCH, Wih + EWD, EWD + HCH,
        (const float*)nullptr, (const float*)nullptr, prew, 4 * HWD, HCH, 1);

    // 6) word LSTM: 64 WGs x 1024 threads
    word_lstm<<<dim3(64), dim3(1024), 0, stream>>>(prew, Whh, (unsigned*)hwv);

    // 7) tag head + log_softmax -> d_out [2048 x 64] f32
    tag_softmax<<<dim3(NWW / 4), dim3(256), 0, stream>>>(hwv, Wtag, btag, (float*)d_out);
}